// Round 7
// baseline (28.520 us; speedup 1.0000x reference)
//
#include <hip/hip_runtime.h>

namespace {
constexpr int Bn = 32, Dn = 64, Hn = 64, Wn = 64;
constexpr int PLANE = Hn * Wn;   // 4096
constexpr int NW  = 8;           // waves per block, splitting d
constexpr int DPW = Dn / NW;     // 8 d-slices per wave
constexpr float SCALE = 0.125f;  // 64^-0.5
}

__global__ __launch_bounds__(512, 8) void dilate_attn_kernel(
    const float* __restrict__ q, const float* __restrict__ k,
    const float* __restrict__ v, float* __restrict__ out)
{
    __shared__ float2 red[NW][9][64];   // 36864 B; 4 blocks/CU = 147 KB

    const int t  = threadIdx.x;
    const int l  = t & 63;
    const int wv = t >> 6;              // wave id -> d-eighth
    const int ci = l & 31;              // lane col-pair index
    const int lr = l >> 5;              // row within stripe
    const int c  = ci * 2;              // first of this lane's 2 pixel cols

    // XCD-chunked swizzle: 1024 blocks -> 128 contiguous (b,stripe) per XCD
    const int bid = blockIdx.x;
    const int swz = (bid & 7) * 128 + (bid >> 3);
    const int b      = swz >> 5;
    const int stripe = swz & 31;
    const int hr     = stripe * 2 + lr; // this lane's pixel row

    const int  base = b * Dn * PLANE;
    const bool ci0 = (ci == 0), ci31 = (ci == 31);

    // shuffle source lanes (wrap/cross-row garbage lands on zeroed positions)
    const int lup = (l - 1) & 63;       // supplies col c-1 (its .y)
    const int ldn = (l + 1) & 63;       // supplies col c+2 (its .x)

    int  koff[3];
    bool rok[3];
#pragma unroll
    for (int di = 0; di < 3; ++di) {
        const int kr = hr - 1 + di;
        rok[di] = (kr >= 0) && (kr < Hn);
        const int krc = min(max(kr, 0), Hn - 1);   // clamped: always in-bounds
        koff[di] = krc * Wn + c;                   // exact float2 at own cols
    }
    const int qoff = hr * Wn + c;

    float a0[9], a1[9];
#pragma unroll
    for (int n = 0; n < 9; ++n) { a0[n] = 0.0f; a1[n] = 0.0f; }

    // -------- Phase 1: partial scores over this wave's 8 d-slices ----------
    {
        const float* kp = k + base + wv * DPW * PLANE;
        const float* qp = q + base + wv * DPW * PLANE;
#pragma unroll 4
        for (int ds = 0; ds < DPW; ++ds) {
            const float2 r0 = *(const float2*)(kp + koff[0]);
            const float2 r1 = *(const float2*)(kp + koff[1]);
            const float2 r2 = *(const float2*)(kp + koff[2]);
            const float2 qv = *(const float2*)(qp + qoff);
            kp += PLANE; qp += PLANE;
#pragma unroll
            for (int di = 0; di < 3; ++di) {
                const float2 rr = (di == 0) ? r0 : (di == 1) ? r1 : r2;
                const float rm = __shfl(rr.y, lup);   // col c-1
                const float rp = __shfl(rr.x, ldn);   // col c+2
                a0[di * 3 + 0] = fmaf(qv.x, rm,   a0[di * 3 + 0]);
                a0[di * 3 + 1] = fmaf(qv.x, rr.x, a0[di * 3 + 1]);
                a0[di * 3 + 2] = fmaf(qv.x, rr.y, a0[di * 3 + 2]);
                a1[di * 3 + 0] = fmaf(qv.y, rr.x, a1[di * 3 + 0]);
                a1[di * 3 + 1] = fmaf(qv.y, rr.y, a1[di * 3 + 1]);
                a1[di * 3 + 2] = fmaf(qv.y, rp,   a1[di * 3 + 2]);
            }
        }
    }

    // -------- cross-wave reduction: wave wv owns window position n=wv ------
#pragma unroll
    for (int n = 0; n < 9; ++n) red[wv][n][l] = make_float2(a0[n], a1[n]);
    __syncthreads();
    {
        float2 s = red[0][wv][l];
#pragma unroll
        for (int sw = 1; sw < NW; ++sw) {
            const float2 p = red[sw][wv][l];
            s.x += p.x; s.y += p.y;
        }
        red[0][wv][l] = s;
        if (wv == NW - 1) {          // wave 7 also reduces n=8
            float2 s8 = red[0][8][l];
#pragma unroll
            for (int sw = 1; sw < NW; ++sw) {
                const float2 p = red[sw][8][l];
                s8.x += p.x; s8.y += p.y;
            }
            red[0][8][l] = s8;
        }
    }
    __syncthreads();
#pragma unroll
    for (int n = 0; n < 9; ++n) {
        const float2 s = red[0][n][l];
        a0[n] = s.x; a1[n] = s.y;
    }

    // -------- zero invalid-position SCORES (reference: q . 0-pad = 0) -------
#pragma unroll
    for (int di = 0; di < 3; ++di)
#pragma unroll
        for (int dj = 0; dj < 3; ++dj) {
            const int n = di * 3 + dj;
            a0[n] = (rok[di] && (dj != 0 || !ci0))  ? a0[n] : 0.0f;
            a1[n] = (rok[di] && (dj != 2 || !ci31)) ? a1[n] : 0.0f;
        }
#pragma unroll
    for (int n = 0; n < 9; ++n) { a0[n] *= SCALE; a1[n] *= SCALE; }
    float m0 = a0[0], m1 = a1[0];
#pragma unroll
    for (int n = 1; n < 9; ++n) { m0 = fmaxf(m0, a0[n]); m1 = fmaxf(m1, a1[n]); }
    float s0 = 0.0f, s1 = 0.0f;
#pragma unroll
    for (int n = 0; n < 9; ++n) {
        a0[n] = __expf(a0[n] - m0); s0 += a0[n];
        a1[n] = __expf(a1[n] - m1); s1 += a1[n];
    }
    const float i0 = 1.0f / s0, i1 = 1.0f / s1;
#pragma unroll
    for (int n = 0; n < 9; ++n) { a0[n] *= i0; a1[n] *= i1; }

    // -------- zero invalid-position WEIGHTS (reference: attn * v=0 there) ---
#pragma unroll
    for (int di = 0; di < 3; ++di)
#pragma unroll
        for (int dj = 0; dj < 3; ++dj) {
            const int n = di * 3 + dj;
            a0[n] = (rok[di] && (dj != 0 || !ci0))  ? a0[n] : 0.0f;
            a1[n] = (rok[di] && (dj != 2 || !ci31)) ? a1[n] : 0.0f;
        }

    // -------- Phase 2: out = attn . v_window for this wave's d-eighth -------
    {
        const float* vp = v + base + wv * DPW * PLANE;
        float*       op = out + base + wv * DPW * PLANE;
#pragma unroll 4
        for (int ds = 0; ds < DPW; ++ds) {
            const float2 r0 = *(const float2*)(vp + koff[0]);
            const float2 r1 = *(const float2*)(vp + koff[1]);
            const float2 r2 = *(const float2*)(vp + koff[2]);
            vp += PLANE;
            float o0 = 0.0f, o1 = 0.0f;
#pragma unroll
            for (int di = 0; di < 3; ++di) {
                const float2 rr = (di == 0) ? r0 : (di == 1) ? r1 : r2;
                const float rm = __shfl(rr.y, lup);   // col c-1
                const float rp = __shfl(rr.x, ldn);   // col c+2
                o0 = fmaf(a0[di * 3 + 0], rm,   o0);
                o0 = fmaf(a0[di * 3 + 1], rr.x, o0);
                o0 = fmaf(a0[di * 3 + 2], rr.y, o0);
                o1 = fmaf(a1[di * 3 + 0], rr.x, o1);
                o1 = fmaf(a1[di * 3 + 1], rr.y, o1);
                o1 = fmaf(a1[di * 3 + 2], rp,   o1);
            }
            *(float2*)(op + qoff) = make_float2(o0, o1);
            op += PLANE;
        }
    }
}

extern "C" void kernel_launch(void* const* d_in, const int* in_sizes, int n_in,
                              void* d_out, int out_size, void* d_ws, size_t ws_size,
                              hipStream_t stream) {
    const float* q = (const float*)d_in[0];
    const float* k = (const float*)d_in[1];
    const float* v = (const float*)d_in[2];
    float* out = (float*)d_out;
    (void)in_sizes; (void)n_in; (void)out_size; (void)d_ws; (void)ws_size;

    const int grid = Bn * 32;  // 1024 blocks x 512 thr -> 4/CU, 32 waves/CU
    dilate_attn_kernel<<<grid, 512, 0, stream>>>(q, k, v, out);
}